// Round 3
// baseline (212.806 us; speedup 1.0000x reference)
//
#include <hip/hip_runtime.h>
#include <hip/hip_bf16.h>
#include <stdint.h>

#define BDIM 4
#define LDIM 128
#define DDIM 256
#define CDIM 512
#define EPSLN 1e-5f
#define NE (BDIM * LDIM * LDIM)
#define SROW 516   // stage row stride (floats): 516%32==4 -> 2-way (free) in D0

typedef float f32x4 __attribute__((ext_vector_type(4)));
typedef short s16x8 __attribute__((ext_vector_type(8)));
typedef int i32x4 __attribute__((ext_vector_type(4)));

__device__ __forceinline__ unsigned short f2bf(float f) {
    unsigned u = __builtin_bit_cast(unsigned, f);
    u += 0x7fffu + ((u >> 16) & 1u);   // RNE (no NaNs in this data)
    return (unsigned short)(u >> 16);
}

__device__ __forceinline__ unsigned pk_bf16(float a, float b) {
    union { __hip_bfloat162 h; unsigned u; } cv;
    cv.h = __float22bfloat162_rn(make_float2(a, b));
    return cv.u;
}

// ---------------------------------------------------------------------------
// Fused prep kernel (UNCHANGED from R2 — proven, −45 µs vs 3-launch version).
// ---------------------------------------------------------------------------
__global__ __launch_bounds__(128) void k_prep(const float* __restrict__ query,
                                              const float* __restrict__ value,
                                              const int* __restrict__ mask,
                                              float* __restrict__ Es,
                                              unsigned short* __restrict__ Qt16,
                                              unsigned short* __restrict__ Vt16) {
    __shared__ __align__(16) char smem[16 * 260 * 4 + 128 * 68 * 4];
    float (*X_s)[260] = (float (*)[260])smem;
    float (*Y_s)[68] = (float (*)[68])(smem + 16 * 260 * 4);
    float (*tile)[33] = (float (*)[33])smem;

    const int t = threadIdx.x;

    if (blockIdx.z >= 4) {
        const int z2 = blockIdx.z - 4;
        const int b = z2 & 3, sel = z2 >> 2;
        const int d0 = blockIdx.x * 32, k0 = blockIdx.y * 32;
        const float* src = sel ? query : value;
        unsigned short* dst16 = sel ? Qt16 : Vt16;
        const int tx = t & 31, ty = t >> 5;
#pragma unroll
        for (int jj = 0; jj < 8; ++jj) {
            int r = ty + jj * 4;
            tile[r][tx] = src[((size_t)(b * LDIM + k0 + r)) * DDIM + d0 + tx];
        }
        __syncthreads();
#pragma unroll
        for (int jj = 0; jj < 8; ++jj) {
            int r = ty + jj * 4;
            size_t o = ((size_t)(b * DDIM + d0 + r)) * LDIM + k0 + tx;
            dst16[o] = f2bf(tile[tx][r]);
        }
        return;
    }

    const int b = blockIdx.z, which = blockIdx.y, it = blockIdx.x;
    const float* X = (which == 0 || which == 2) ? query : value;  // 0:QV 1:VV 2:QQ 3:VQ
    const float* Y = (which <= 1) ? value : query;
    const float* Xb = X + (size_t)b * LDIM * DDIM;
    const float* Yb = Y + (size_t)b * LDIM * DDIM;

    const int i0 = it * 16;
    const int iq = (t >> 5) << 2;
    const int kl = t & 31;

#pragma unroll
    for (int u = 0; u < 8; ++u) {
        int ch = u * 128 + t;
        int row = ch >> 6;
        int cc = (ch & 63) << 2;
        *(f32x4*)&X_s[row][cc] = *(const f32x4*)(Xb + (size_t)(i0 + row) * DDIM + cc);
    }

    float acc[4][4] = {};
#pragma unroll 1
    for (int ct = 0; ct < 4; ++ct) {
#pragma unroll
        for (int u = 0; u < 16; ++u) {
            int ch = u * 128 + t;
            int row = ch >> 4;
            int cc = (ch & 15) << 2;
            *(f32x4*)&Y_s[row][cc] = *(const f32x4*)(Yb + (size_t)row * DDIM + ct * 64 + cc);
        }
        __syncthreads();
#pragma unroll
        for (int u = 0; u < 16; ++u) {
            const int c = u * 4;
            f32x4 xv[4], yv[4];
#pragma unroll
            for (int ii = 0; ii < 4; ++ii) xv[ii] = *(const f32x4*)&X_s[iq + ii][ct * 64 + c];
#pragma unroll
            for (int kk = 0; kk < 4; ++kk) yv[kk] = *(const f32x4*)&Y_s[kl + 32 * kk][c];
#pragma unroll
            for (int ii = 0; ii < 4; ++ii)
#pragma unroll
                for (int kk = 0; kk < 4; ++kk)
#pragma unroll
                    for (int e = 0; e < 4; ++e)
                        acc[ii][kk] += xv[ii][e] * yv[kk][e];
        }
        __syncthreads();
    }

    int mk[4];
#pragma unroll
    for (int kk = 0; kk < 4; ++kk) mk[kk] = mask[b * LDIM + kl + 32 * kk];

    float* Eg = Es + (size_t)which * NE + (size_t)b * (LDIM * LDIM);
#pragma unroll
    for (int ii = 0; ii < 4; ++ii) {
        float lg[4];
        float mx = -3.0e38f;
#pragma unroll
        for (int kk = 0; kk < 4; ++kk) {
            lg[kk] = 0.5f * acc[ii][kk];
            if (mk[kk] != 0) mx = fmaxf(mx, lg[kk]);
        }
#pragma unroll
        for (int o = 16; o >= 1; o >>= 1) mx = fmaxf(mx, __shfl_xor(mx, o, 64));
#pragma unroll
        for (int kk = 0; kk < 4; ++kk)
            Eg[(size_t)(i0 + iq + ii) * LDIM + kl + 32 * kk] =
                (mk[kk] != 0) ? __expf(lg[kk] - mx) : 0.0f;
    }
}

// ---------------------------------------------------------------------------
// Main fused kernel v3: OCCUPANCY RESTRUCTURE.
// Theory: at 2 blocks/CU (2 waves/SIMD) the per-block latency chain is fully
// exposed. Changes vs proven R2 k_main:
//  - i-tile 32 -> 16 rows: acc 64->32 VGPR, stage 66->33 KB, grid (8,128,4).
//  - B-frag kc-split (load kc01, MFMA, reload same regs kc23, MFMA):
//    bfr 128->64 VGPR. Per-acc kc order 0,1,2,3 preserved -> bit-identical MFMA.
//  - LN sums moved out of phase E's 12-deep serial ds_swizzle chain: computed
//    at D0 as 8-element register partials + 4-level 16-lane shuffle + 512 B
//    cross-wave LDS reduce. Phase E has NO shuffles.
// Budget: VGPR ~160 (3 waves/SIMD, __launch_bounds__(256,3)), LDS ~37 KB
// (4 blocks/CU) -> occupancy 8 -> 12 waves/CU.
// MFMA 16x16x32 bf16: A[m=lane&15][k=quad*8+u], B[k][n=lane&15],
//                     C row = quad*4+reg, col = lane&15.  (verified R1)
// ---------------------------------------------------------------------------
__global__ __launch_bounds__(256, 3) void k_main(const float* __restrict__ E1,
                                                 const unsigned short* __restrict__ Vt16,
                                                 const unsigned short* __restrict__ Qt16,
                                                 const int* __restrict__ mask,
                                                 const float* __restrict__ nw,
                                                 const float* __restrict__ nb,
                                                 float* __restrict__ out) {
    // union: P buffers (8704 B) live inside the 33024 B staging tile
    __shared__ __align__(16) char smem[16 * SROW * 4];
    unsigned short (*P_s)[136] = (unsigned short (*)[136])smem;
    unsigned short (*Pq_s)[136] = (unsigned short (*)[136])(smem + 16 * 136 * 2);
    float (*stage)[SROW] = (float (*)[SROW])smem;
    __shared__ float wln[CDIM], bln[CDIM];
    __shared__ float zinv_s[32];                       // [path*16 + row]
    __shared__ __align__(16) float red[16][4][2];      // [row][wave][s1,s2]
    __shared__ float maskv[16];

    const int tid = threadIdx.x;
    const int i0 = blockIdx.x * 16;
    const int j = blockIdx.y;
    const int b = blockIdx.z;

    const int lane = tid & 63;
    const int q = lane >> 4;
    const int l15 = lane & 15;
    const int wv = tid >> 6;
    const int path = wv >> 1;
    const int nh = wv & 1;

    const float* E2 = E1 + NE;
    const float* E1q = E1 + 2 * NE;
    const float* E2q = E1 + 3 * NE;

    wln[tid] = nw[tid]; wln[tid + 256] = nw[tid + 256];
    bln[tid] = nb[tid]; bln[tid + 256] = nb[tid + 256];
    if (tid < 16) maskv[tid] = (mask[b * LDIM + i0 + tid] != 0) ? 1.0f : 0.0f;

    // B-fragment preload, kc half 0 (k 0..63 of this wave's 128-col quarter)
    const unsigned short* bsrc = (path ? Qt16 : Vt16) +
                                 (size_t)b * DDIM * LDIM + (size_t)(nh * 128) * LDIM;
    s16x8 bfr[8][2];
#pragma unroll
    for (int nt = 0; nt < 8; ++nt)
#pragma unroll
        for (int kc = 0; kc < 2; ++kc)
            bfr[nt][kc] = *(const s16x8*)(bsrc + (size_t)(nt * 16 + l15) * LDIM + kc * 32 + q * 8);

    // ---- phase A: P = E1 (.) E2[j] (packed bf16 -> LDS) + f32 Z row sums ----
    // 16 threads per row, 8 floats each.
    {
        const int m = tid >> 4;
        const int k0 = (tid & 15) * 8;
        const float* e1 = E1 + ((size_t)(b * LDIM + i0 + m)) * LDIM + k0;
        const float* e1q = E1q + ((size_t)(b * LDIM + i0 + m)) * LDIM + k0;
        const float* e2 = E2 + ((size_t)(b * LDIM + j)) * LDIM + k0;
        const float* e2q = E2q + ((size_t)(b * LDIM + j)) * LDIM + k0;
        union { unsigned u32[4]; s16x8 v; } tp, tq;
        float s = 0.f, sq = 0.f;
#pragma unroll
        for (int u4 = 0; u4 < 8; u4 += 4) {
            f32x4 a = *(const f32x4*)(e1 + u4);
            f32x4 c = *(const f32x4*)(e2 + u4);
            f32x4 aq = *(const f32x4*)(e1q + u4);
            f32x4 cq = *(const f32x4*)(e2q + u4);
            float p0 = a[0] * c[0], p1 = a[1] * c[1], p2 = a[2] * c[2], p3 = a[3] * c[3];
            float q0 = aq[0] * cq[0], q1 = aq[1] * cq[1], q2 = aq[2] * cq[2], q3 = aq[3] * cq[3];
            s += (p0 + p1) + (p2 + p3);
            sq += (q0 + q1) + (q2 + q3);
            tp.u32[u4 / 2] = pk_bf16(p0, p1);
            tp.u32[u4 / 2 + 1] = pk_bf16(p2, p3);
            tq.u32[u4 / 2] = pk_bf16(q0, q1);
            tq.u32[u4 / 2 + 1] = pk_bf16(q2, q3);
        }
        *(s16x8*)&P_s[m][k0] = tp.v;
        *(s16x8*)&Pq_s[m][k0] = tq.v;
        s += __shfl_xor(s, 1, 64); s += __shfl_xor(s, 2, 64);
        s += __shfl_xor(s, 4, 64); s += __shfl_xor(s, 8, 64);
        sq += __shfl_xor(sq, 1, 64); sq += __shfl_xor(sq, 2, 64);
        sq += __shfl_xor(sq, 4, 64); sq += __shfl_xor(sq, 8, 64);
        if ((tid & 15) == 0) { zinv_s[m] = 1.0f / s; zinv_s[16 + m] = 1.0f / sq; }
    }
    __syncthreads();

    // ---- phase B: MFMA, kc-split (B regs reused between halves) ----
    f32x4 acc[8];
#pragma unroll
    for (int nt = 0; nt < 8; ++nt) acc[nt] = (f32x4){0.f, 0.f, 0.f, 0.f};

    const unsigned short(*As)[136] = path ? Pq_s : P_s;
    {
        s16x8 a0 = *(const s16x8*)&As[l15][0 * 32 + q * 8];
        s16x8 a1 = *(const s16x8*)&As[l15][1 * 32 + q * 8];
#pragma unroll
        for (int nt = 0; nt < 8; ++nt)
            acc[nt] = __builtin_amdgcn_mfma_f32_16x16x32_bf16(a0, bfr[nt][0], acc[nt], 0, 0, 0);
#pragma unroll
        for (int nt = 0; nt < 8; ++nt)
            acc[nt] = __builtin_amdgcn_mfma_f32_16x16x32_bf16(a1, bfr[nt][1], acc[nt], 0, 0, 0);
        // reload same registers with kc half 1 (k 64..127)
#pragma unroll
        for (int nt = 0; nt < 8; ++nt)
#pragma unroll
            for (int kc = 0; kc < 2; ++kc)
                bfr[nt][kc] = *(const s16x8*)(bsrc + (size_t)(nt * 16 + l15) * LDIM +
                                              (kc + 2) * 32 + q * 8);
        s16x8 a2 = *(const s16x8*)&As[l15][2 * 32 + q * 8];
        s16x8 a3 = *(const s16x8*)&As[l15][3 * 32 + q * 8];
#pragma unroll
        for (int nt = 0; nt < 8; ++nt)
            acc[nt] = __builtin_amdgcn_mfma_f32_16x16x32_bf16(a2, bfr[nt][0], acc[nt], 0, 0, 0);
#pragma unroll
        for (int nt = 0; nt < 8; ++nt)
            acc[nt] = __builtin_amdgcn_mfma_f32_16x16x32_bf16(a3, bfr[nt][1], acc[nt], 0, 0, 0);
    }
    __syncthreads();   // all MFMA reads of P done -> P dead, stage may clobber

    // ---- phase D0: normalized values -> stage + LN partial sums ----
#pragma unroll
    for (int reg = 0; reg < 4; ++reg) {
        const int row = q * 4 + reg;
        const float zv = zinv_s[path * 16 + row];
        float s1 = 0.f, s2 = 0.f;
#pragma unroll
        for (int nt = 0; nt < 8; ++nt) {
            const int c = path * 256 + nh * 128 + nt * 16 + l15;
            const float v = acc[nt][reg] * zv;
            stage[row][c] = v;
            s1 += v; s2 += v * v;
        }
        // 16-lane (l15) reduce: this wave's 128-col partial for `row`
        s1 += __shfl_xor(s1, 1, 64); s2 += __shfl_xor(s2, 1, 64);
        s1 += __shfl_xor(s1, 2, 64); s2 += __shfl_xor(s2, 2, 64);
        s1 += __shfl_xor(s1, 4, 64); s2 += __shfl_xor(s2, 4, 64);
        s1 += __shfl_xor(s1, 8, 64); s2 += __shfl_xor(s2, 8, 64);
        if (l15 == 0) { red[row][wv][0] = s1; red[row][wv][1] = s2; }
    }
    __syncthreads();

    // ---- phase E: per-wave rows (4 each): finalize LN from red, store ----
    {
        const f32x4 w0 = *(const f32x4*)&wln[lane * 4];
        const f32x4 b0 = *(const f32x4*)&bln[lane * 4];
        const f32x4 w1 = *(const f32x4*)&wln[256 + lane * 4];
        const f32x4 b1 = *(const f32x4*)&bln[256 + lane * 4];
#pragma unroll
        for (int rr = 0; rr < 4; ++rr) {
            const int row = wv * 4 + rr;
            const f32x4 ra = *(const f32x4*)&red[row][0][0];   // s1_0,s2_0,s1_1,s2_1
            const f32x4 rb = *(const f32x4*)&red[row][2][0];   // s1_2,s2_2,s1_3,s2_3
            const float s1t = (ra[0] + ra[2]) + (rb[0] + rb[2]);
            const float s2t = (ra[1] + ra[3]) + (rb[1] + rb[3]);
            const float mean = s1t * (1.0f / 512.0f);
            const float var = s2t * (1.0f / 512.0f) - mean * mean;
            const float rstd = rsqrtf(var + EPSLN);
            const float mf = maskv[row];
            const f32x4 v0 = *(const f32x4*)&stage[row][lane * 4];
            const f32x4 v1 = *(const f32x4*)&stage[row][256 + lane * 4];
            float* orow = out + (((size_t)(b * LDIM + i0 + row)) * LDIM + j) * CDIM;
            f32x4 o0, o1;
#pragma unroll
            for (int u = 0; u < 4; ++u) {
                o0[u] = ((v0[u] - mean) * rstd * w0[u] + b0[u]) * mf;
                o1[u] = ((v1[u] - mean) * rstd * w1[u] + b1[u]) * mf;
            }
            *(f32x4*)&orow[lane * 4] = o0;
            *(f32x4*)&orow[256 + lane * 4] = o1;
        }
    }
}

// ---------------------------------------------------------------------------
extern "C" void kernel_launch(void* const* d_in, const int* in_sizes, int n_in,
                              void* d_out, int out_size, void* d_ws, size_t ws_size,
                              hipStream_t stream) {
    const float* query = (const float*)d_in[0];
    const float* value = (const float*)d_in[1];
    const int* mask = (const int*)d_in[2];
    const float* nw = (const float*)d_in[3];
    const float* nb = (const float*)d_in[4];
    float* out = (float*)d_out;

    char* ws = (char*)d_ws;
    const size_t NT = (size_t)BDIM * DDIM * LDIM;   // 131072 elems per transposed mat

    float* Es = (float*)ws;                                       // 4 x 256 KiB
    unsigned short* Vt16 = (unsigned short*)(ws + 4 * (size_t)NE * 4);
    unsigned short* Qt16 = Vt16 + NT;                             // 256 KiB each
    // total ws use: 1.5 MiB

    k_prep<<<dim3(8, 4, 12), 128, 0, stream>>>(query, value, mask, Es, Qt16, Vt16);
    k_main<<<dim3(8, 128, 4), 256, 0, stream>>>(Es, Vt16, Qt16, mask, nw, nb, out);
}

// Round 4
// 192.012 us; speedup vs baseline: 1.1083x; 1.1083x over previous
//
#include <hip/hip_runtime.h>
#include <hip/hip_bf16.h>
#include <stdint.h>

#define BDIM 4
#define LDIM 128
#define DDIM 256
#define CDIM 512
#define EPSLN 1e-5f
#define NE (BDIM * LDIM * LDIM)
#define SROW 516   // stage row stride (floats): 516%32==4 -> 2-way (free) in D0

typedef float f32x4 __attribute__((ext_vector_type(4)));
typedef short s16x8 __attribute__((ext_vector_type(8)));
typedef int i32x4 __attribute__((ext_vector_type(4)));

__device__ __forceinline__ unsigned short f2bf(float f) {
    unsigned u = __builtin_bit_cast(unsigned, f);
    u += 0x7fffu + ((u >> 16) & 1u);   // RNE (no NaNs in this data)
    return (unsigned short)(u >> 16);
}

__device__ __forceinline__ unsigned pk_bf16(float a, float b) {
    union { __hip_bfloat162 h; unsigned u; } cv;
    cv.h = __float22bfloat162_rn(make_float2(a, b));
    return cv.u;
}

// ---------------------------------------------------------------------------
// Fused prep kernel v2.  Grid (16, 4, 8), 128 threads.
//   z < 4 : GRAM duty, now 8 i-rows/block x 16 i-tiles (x) x which (y) x b (z)
//           = 256 blocks (was 128 x 16 rows).  Per-thread FMA 4096 -> 2048,
//           concurrency 2x.  Ascending-c FMA chain per (i,k) preserved ->
//           E output bit-identical to R2.  LDS 43 KB -> 3 blocks/CU.
//   z >= 4: TRANSPOSE duty (bf16 cast), 256 blocks via idx = (z-4)*64+y*16+x.
// ---------------------------------------------------------------------------
__global__ __launch_bounds__(128) void k_prep(const float* __restrict__ query,
                                              const float* __restrict__ value,
                                              const int* __restrict__ mask,
                                              float* __restrict__ Es,
                                              unsigned short* __restrict__ Qt16,
                                              unsigned short* __restrict__ Vt16) {
    // gram: X_s[8][260] (8320 B) + Y_s[128][68] (34816 B) = 43136 B
    // transpose tile[32][33] (4224 B) overlays the same space
    __shared__ __align__(16) char smem[8 * 260 * 4 + 128 * 68 * 4];
    float (*X_s)[260] = (float (*)[260])smem;
    float (*Y_s)[68] = (float (*)[68])(smem + 8 * 260 * 4);
    float (*tile)[33] = (float (*)[33])smem;

    const int t = threadIdx.x;

    if (blockIdx.z >= 4) {
        // ---------------- transpose + bf16 cast (32x32 tile) ----------------
        const int idx = (blockIdx.z - 4) * 64 + blockIdx.y * 16 + blockIdx.x;  // 0..255
        const int sel = idx >> 7;
        const int b = (idx >> 5) & 3;
        const int d0 = ((idx >> 2) & 7) * 32;
        const int k0 = (idx & 3) * 32;
        const float* src = sel ? query : value;
        unsigned short* dst16 = sel ? Qt16 : Vt16;
        const int tx = t & 31, ty = t >> 5;   // ty in [0,4)
#pragma unroll
        for (int jj = 0; jj < 8; ++jj) {
            int r = ty + jj * 4;
            tile[r][tx] = src[((size_t)(b * LDIM + k0 + r)) * DDIM + d0 + tx];
        }
        __syncthreads();
#pragma unroll
        for (int jj = 0; jj < 8; ++jj) {
            int r = ty + jj * 4;
            size_t o = ((size_t)(b * DDIM + d0 + r)) * LDIM + k0 + tx;
            dst16[o] = f2bf(tile[tx][r]);
        }
        return;
    }

    // ---------------- gram + E build (8 i-rows per block) ----------------
    const int b = blockIdx.z, which = blockIdx.y, it = blockIdx.x;
    const float* X = (which == 0 || which == 2) ? query : value;  // 0:QV 1:VV 2:QQ 3:VQ
    const float* Y = (which <= 1) ? value : query;
    const float* Xb = X + (size_t)b * LDIM * DDIM;
    const float* Yb = Y + (size_t)b * LDIM * DDIM;

    const int i0 = it * 8;
    const int iq = (t >> 5) * 2;      // this thread's 2 i-rows (local)
    const int kl = t & 31;            // k = kl + 32*kk, kk in [0,4)

    // stage X rows [8][256] -> X_s (512 f32x4 chunks / 128 thr = 4 each)
#pragma unroll
    for (int u = 0; u < 4; ++u) {
        int ch = u * 128 + t;
        int row = ch >> 6;
        int cc = (ch & 63) << 2;
        *(f32x4*)&X_s[row][cc] = *(const f32x4*)(Xb + (size_t)(i0 + row) * DDIM + cc);
    }

    float acc[2][4] = {};
#pragma unroll 1
    for (int ct = 0; ct < 4; ++ct) {
        // stage Y c-tile [128][64] -> Y_s
#pragma unroll
        for (int u = 0; u < 16; ++u) {
            int ch = u * 128 + t;
            int row = ch >> 4;
            int cc = (ch & 15) << 2;
            *(f32x4*)&Y_s[row][cc] = *(const f32x4*)(Yb + (size_t)row * DDIM + ct * 64 + cc);
        }
        __syncthreads();
#pragma unroll
        for (int u = 0; u < 16; ++u) {
            const int c = u * 4;
            f32x4 xv[2], yv[4];
#pragma unroll
            for (int ii = 0; ii < 2; ++ii) xv[ii] = *(const f32x4*)&X_s[iq + ii][ct * 64 + c];
#pragma unroll
            for (int kk = 0; kk < 4; ++kk) yv[kk] = *(const f32x4*)&Y_s[kl + 32 * kk][c];
#pragma unroll
            for (int ii = 0; ii < 2; ++ii)
#pragma unroll
                for (int kk = 0; kk < 4; ++kk)
#pragma unroll
                    for (int e = 0; e < 4; ++e)
                        acc[ii][kk] += xv[ii][e] * yv[kk][e];   // ascending-c, bit-identical
        }
        __syncthreads();
    }

    int mk[4];
#pragma unroll
    for (int kk = 0; kk < 4; ++kk) mk[kk] = mask[b * LDIM + kl + 32 * kk];

    float* Eg = Es + (size_t)which * NE + (size_t)b * (LDIM * LDIM);
#pragma unroll
    for (int ii = 0; ii < 2; ++ii) {
        float lg[4];
        float mx = -3.0e38f;
#pragma unroll
        for (int kk = 0; kk < 4; ++kk) {
            lg[kk] = 0.5f * acc[ii][kk];
            if (mk[kk] != 0) mx = fmaxf(mx, lg[kk]);
        }
#pragma unroll
        for (int o = 16; o >= 1; o >>= 1) mx = fmaxf(mx, __shfl_xor(mx, o, 64));
#pragma unroll
        for (int kk = 0; kk < 4; ++kk)
            Eg[(size_t)(i0 + iq + ii) * LDIM + kl + 32 * kk] =
                (mk[kk] != 0) ? __expf(lg[kk] - mx) : 0.0f;
    }
}

// ---------------------------------------------------------------------------
// Main fused kernel v4 = proven R2 structure (i-tile 32, 1 j/blk, 2048 blocks,
// full bfr[8][4] preload — both structural neighbors regressed R1/R3) with ONE
// change: LN partial sums computed at phase D0 (4-level 16-lane shuffles,
// independent chains interleaved with stage writes) + 1 KB red[] cross-wave
// reduce.  Phase E loses its 96-deep serial shuffle chain: broadcast red
// reads + affine + coalesced f32x4 stores only.
// MFMA 16x16x32 bf16: A[m=lane&15][k=quad*8+u], B[k][n=lane&15],
//                     C row = quad*4+reg, col = lane&15.  (verified R1)
// LDS ~71.5 KB -> still 2 blocks/CU.
// ---------------------------------------------------------------------------
__global__ __launch_bounds__(256, 2) void k_main(const float* __restrict__ E1,
                                                 const unsigned short* __restrict__ Vt16,
                                                 const unsigned short* __restrict__ Qt16,
                                                 const int* __restrict__ mask,
                                                 const float* __restrict__ nw,
                                                 const float* __restrict__ nb,
                                                 float* __restrict__ out) {
    // union: P buffers (17408 B) live inside the 66048 B staging tile
    __shared__ __align__(16) char smem[32 * SROW * 4];
    unsigned short (*P_s)[136] = (unsigned short (*)[136])smem;
    unsigned short (*Pq_s)[136] = (unsigned short (*)[136])(smem + 32 * 136 * 2);
    float (*stage)[SROW] = (float (*)[SROW])smem;
    __shared__ float wln[CDIM], bln[CDIM];
    __shared__ float zinv_s[64];
    __shared__ __align__(16) float red[32][4][2];   // [row][wave][s1,s2]
    __shared__ float maskv[32];

    const int tid = threadIdx.x;
    const int i0 = blockIdx.x * 32;
    const int j = blockIdx.y;
    const int b = blockIdx.z;

    const int lane = tid & 63;
    const int q = lane >> 4;
    const int l15 = lane & 15;
    const int wv = tid >> 6;
    const int path = wv >> 1;
    const int nh = wv & 1;

    const float* E2 = E1 + NE;
    const float* E1q = E1 + 2 * NE;
    const float* E2q = E1 + 3 * NE;

    wln[tid] = nw[tid]; wln[tid + 256] = nw[tid + 256];
    bln[tid] = nb[tid]; bln[tid + 256] = nb[tid + 256];
    if (tid < 32) maskv[tid] = (mask[b * LDIM + i0 + tid] != 0) ? 1.0f : 0.0f;

    // B-fragment preload: this wave's 128-col x 128-k quarter (from L2).
    const unsigned short* bsrc = (path ? Qt16 : Vt16) +
                                 (size_t)b * DDIM * LDIM + (size_t)(nh * 128) * LDIM;
    s16x8 bfr[8][4];
#pragma unroll
    for (int nt = 0; nt < 8; ++nt)
#pragma unroll
        for (int kc = 0; kc < 4; ++kc)
            bfr[nt][kc] = *(const s16x8*)(bsrc + (size_t)(nt * 16 + l15) * LDIM + kc * 32 + q * 8);

    // ---- phase A: P = E1 (.) E2[j] (packed bf16 -> LDS) + f32 Z row sums ----
    {
        const int m = tid >> 3;
        const int k0 = (tid & 7) * 16;
        const float* e1 = E1 + ((size_t)(b * LDIM + i0 + m)) * LDIM + k0;
        const float* e1q = E1q + ((size_t)(b * LDIM + i0 + m)) * LDIM + k0;
        const float* e2 = E2 + ((size_t)(b * LDIM + j)) * LDIM + k0;
        const float* e2q = E2q + ((size_t)(b * LDIM + j)) * LDIM + k0;
        union { unsigned u32[8]; s16x8 v[2]; } tp, tq;
        float s = 0.f, sq = 0.f;
#pragma unroll
        for (int u4 = 0; u4 < 16; u4 += 4) {
            f32x4 a = *(const f32x4*)(e1 + u4);
            f32x4 c = *(const f32x4*)(e2 + u4);
            f32x4 aq = *(const f32x4*)(e1q + u4);
            f32x4 cq = *(const f32x4*)(e2q + u4);
            float p0 = a[0] * c[0], p1 = a[1] * c[1], p2 = a[2] * c[2], p3 = a[3] * c[3];
            float q0 = aq[0] * cq[0], q1 = aq[1] * cq[1], q2 = aq[2] * cq[2], q3 = aq[3] * cq[3];
            s += (p0 + p1) + (p2 + p3);
            sq += (q0 + q1) + (q2 + q3);
            tp.u32[u4 / 2] = pk_bf16(p0, p1);
            tp.u32[u4 / 2 + 1] = pk_bf16(p2, p3);
            tq.u32[u4 / 2] = pk_bf16(q0, q1);
            tq.u32[u4 / 2 + 1] = pk_bf16(q2, q3);
        }
        *(s16x8*)&P_s[m][k0] = tp.v[0];
        *(s16x8*)&P_s[m][k0 + 8] = tp.v[1];
        *(s16x8*)&Pq_s[m][k0] = tq.v[0];
        *(s16x8*)&Pq_s[m][k0 + 8] = tq.v[1];
        s += __shfl_xor(s, 1, 64); s += __shfl_xor(s, 2, 64); s += __shfl_xor(s, 4, 64);
        sq += __shfl_xor(sq, 1, 64); sq += __shfl_xor(sq, 2, 64); sq += __shfl_xor(sq, 4, 64);
        if ((tid & 7) == 0) { zinv_s[m] = 1.0f / s; zinv_s[32 + m] = 1.0f / sq; }
    }
    __syncthreads();

    // ---- phase B: MFMA (B-frags in registers, no staging barriers) ----
    f32x4 acc[2][8];
#pragma unroll
    for (int mt = 0; mt < 2; ++mt)
#pragma unroll
        for (int nt = 0; nt < 8; ++nt) acc[mt][nt] = (f32x4){0.f, 0.f, 0.f, 0.f};

    const unsigned short(*As)[136] = path ? Pq_s : P_s;
#pragma unroll
    for (int kc = 0; kc < 4; ++kc) {
        const s16x8 a0 = *(const s16x8*)&As[l15][kc * 32 + q * 8];
        const s16x8 a1 = *(const s16x8*)&As[16 + l15][kc * 32 + q * 8];
#pragma unroll
        for (int nt = 0; nt < 8; ++nt) {
            acc[0][nt] = __builtin_amdgcn_mfma_f32_16x16x32_bf16(a0, bfr[nt][kc], acc[0][nt], 0, 0, 0);
            acc[1][nt] = __builtin_amdgcn_mfma_f32_16x16x32_bf16(a1, bfr[nt][kc], acc[1][nt], 0, 0, 0);
        }
    }
    __syncthreads();   // all MFMA reads of P done -> P dead, stage may clobber

    // ---- phase D0: normalized values -> stage + LN partial sums ----
#pragma unroll
    for (int mt = 0; mt < 2; ++mt) {
#pragma unroll
        for (int reg = 0; reg < 4; ++reg) {
            const int row = mt * 16 + q * 4 + reg;
            const float zv = zinv_s[path * 32 + row];
            float s1 = 0.f, s2 = 0.f;
#pragma unroll
            for (int nt = 0; nt < 8; ++nt) {
                const int c = path * 256 + nh * 128 + nt * 16 + l15;
                const float v = acc[mt][nt][reg] * zv;
                stage[row][c] = v;
                s1 += v; s2 += v * v;
            }
            // 16-lane reduce within the l15 group (this wave's 128-col partial)
            s1 += __shfl_xor(s1, 1, 64); s2 += __shfl_xor(s2, 1, 64);
            s1 += __shfl_xor(s1, 2, 64); s2 += __shfl_xor(s2, 2, 64);
            s1 += __shfl_xor(s1, 4, 64); s2 += __shfl_xor(s2, 4, 64);
            s1 += __shfl_xor(s1, 8, 64); s2 += __shfl_xor(s2, 8, 64);
            if (l15 == 0) { red[row][wv][0] = s1; red[row][wv][1] = s2; }
        }
    }
    __syncthreads();

    // ---- phase E: per-wave rows: finalize LN from red (broadcast), store ----
    {
        const f32x4 w0 = *(const f32x4*)&wln[lane * 4];
        const f32x4 b0 = *(const f32x4*)&bln[lane * 4];
        const f32x4 w1 = *(const f32x4*)&wln[256 + lane * 4];
        const f32x4 b1 = *(const f32x4*)&bln[256 + lane * 4];
#pragma unroll
        for (int rr = 0; rr < 8; ++rr) {
            const int row = wv * 8 + rr;
            const f32x4 ra = *(const f32x4*)&red[row][0][0];   // s1_0,s2_0,s1_1,s2_1
            const f32x4 rb = *(const f32x4*)&red[row][2][0];   // s1_2,s2_2,s1_3,s2_3
            const float s1t = (ra[0] + ra[2]) + (rb[0] + rb[2]);
            const float s2t = (ra[1] + ra[3]) + (rb[1] + rb[3]);
            const float mean = s1t * (1.0f / 512.0f);
            const float var = s2t * (1.0f / 512.0f) - mean * mean;
            const float rstd = rsqrtf(var + EPSLN);
            const float mf = maskv[row];
            const f32x4 v0 = *(const f32x4*)&stage[row][lane * 4];
            const f32x4 v1 = *(const f32x4*)&stage[row][256 + lane * 4];
            float* orow = out + (((size_t)(b * LDIM + i0 + row)) * LDIM + j) * CDIM;
            f32x4 o0, o1;
#pragma unroll
            for (int u = 0; u < 4; ++u) {
                o0[u] = ((v0[u] - mean) * rstd * w0[u] + b0[u]) * mf;
                o1[u] = ((v1[u] - mean) * rstd * w1[u] + b1[u]) * mf;
            }
            *(f32x4*)&orow[lane * 4] = o0;
            *(f32x4*)&orow[256 + lane * 4] = o1;
        }
    }
}

// ---------------------------------------------------------------------------
extern "C" void kernel_launch(void* const* d_in, const int* in_sizes, int n_in,
                              void* d_out, int out_size, void* d_ws, size_t ws_size,
                              hipStream_t stream) {
    const float* query = (const float*)d_in[0];
    const float* value = (const float*)d_in[1];
    const int* mask = (const int*)d_in[2];
    const float* nw = (const float*)d_in[3];
    const float* nb = (const float*)d_in[4];
    float* out = (float*)d_out;

    char* ws = (char*)d_ws;
    const size_t NT = (size_t)BDIM * DDIM * LDIM;   // 131072 elems per transposed mat

    float* Es = (float*)ws;                                       // 4 x 256 KiB
    unsigned short* Vt16 = (unsigned short*)(ws + 4 * (size_t)NE * 4);
    unsigned short* Qt16 = Vt16 + NT;                             // 256 KiB each
    // total ws use: 1.5 MiB

    k_prep<<<dim3(16, 4, 8), 128, 0, stream>>>(query, value, mask, Es, Qt16, Vt16);
    k_main<<<dim3(4, 128, 4), 256, 0, stream>>>(Es, Vt16, Qt16, mask, nw, nb, out);
}